// Round 9
// baseline (1682.595 us; speedup 1.0000x reference)
//
#include <hip/hip_runtime.h>
#include <hip/hip_bf16.h>
#include <cmath>

// Problem: N=64, T=512, D=512, H=512
//   xw = x @ Wx + b                 (parallel GEMM, kernel A -> d_out)
//   h_t = tanh(xw_t + h_{t-1} @ Wh) (sequential, kernel B)
//
// R9: contribution-passing recurrence. 4 wgs/seq; wg p owns k-ROWS
// [128p,+128) of Wh (thread j holds Wh[k-slice][j] in wv[128]) and output
// cols [128p,+128). Per step each thread computes its column's partial dot
// from LOCAL data only (own h piece, LDS broadcast); 384 publisher threads
// ship tagged {t+1,contrib} 8B words straight to L3; 128 owner threads poll
// their 3 adjacent slots and finish with 3 adds + tanh. This moves the FMA
// and the 8-way reduce OFF the post-communication critical path (R5 paid
// arrival -> FMA 550 -> barrier+store-drain ~950 -> reduce 250 -> publish;
// here arrival -> 150 cyc -> next step). Publisher store-drain overlaps the
// owners' poll; the out-store is deferred one step so its drain hides under
// the next transit window. One barrier per step.
// L2-exchange attempts (R6 sc0, R8 wg-scope RMW) are refuted; L3 relaxed
// agent atomics with tag-in-data are the proven primitive (R4/R5).

#define DH     512
#define NSEQ   64
#define TSTEPS 512
#define MTOT   32768   // N*T

typedef float v2f __attribute__((ext_vector_type(2)));

// ---------------- Kernel A: xw = x @ Wx + b  (fp32 LDS-tiled GEMM) ----------
__global__ __launch_bounds__(256) void xw_gemm(
    const float* __restrict__ X,    // (32768, 512)
    const float* __restrict__ Wx,   // (512, 512)
    const float* __restrict__ b,    // (512,)
    float* __restrict__ XW)         // (32768, 512) == d_out
{
    __shared__ float As[16][64];
    __shared__ float Bs[16][64];

    const int bm = blockIdx.x * 64;
    const int bn = blockIdx.y * 64;
    const int tid = threadIdx.x;
    const int tr = tid >> 4;
    const int tc = tid & 15;

    float acc[4][4] = {};

    for (int k0 = 0; k0 < DH; k0 += 16) {
        {
            int m  = tid >> 2;
            int kk = (tid & 3) * 4;
            const float4 v = *(const float4*)&X[(size_t)(bm + m) * DH + k0 + kk];
            As[kk + 0][m] = v.x; As[kk + 1][m] = v.y;
            As[kk + 2][m] = v.z; As[kk + 3][m] = v.w;
        }
        {
            int k  = tid >> 4;
            int j4 = (tid & 15) * 4;
            *(float4*)&Bs[k][j4] = *(const float4*)&Wx[(size_t)(k0 + k) * DH + bn + j4];
        }
        __syncthreads();

        #pragma unroll
        for (int k = 0; k < 16; ++k) {
            float a0 = As[k][tr * 4 + 0], a1 = As[k][tr * 4 + 1];
            float a2 = As[k][tr * 4 + 2], a3 = As[k][tr * 4 + 3];
            float b0 = Bs[k][tc * 4 + 0], b1 = Bs[k][tc * 4 + 1];
            float b2 = Bs[k][tc * 4 + 2], b3 = Bs[k][tc * 4 + 3];
            acc[0][0] += a0 * b0; acc[0][1] += a0 * b1; acc[0][2] += a0 * b2; acc[0][3] += a0 * b3;
            acc[1][0] += a1 * b0; acc[1][1] += a1 * b1; acc[1][2] += a1 * b2; acc[1][3] += a1 * b3;
            acc[2][0] += a2 * b0; acc[2][1] += a2 * b1; acc[2][2] += a2 * b2; acc[2][3] += a2 * b3;
            acc[3][0] += a3 * b0; acc[3][1] += a3 * b1; acc[3][2] += a3 * b2; acc[3][3] += a3 * b3;
        }
        __syncthreads();
    }

    #pragma unroll
    for (int i = 0; i < 4; ++i) {
        const size_t row = (size_t)(bm + tr * 4 + i);
        #pragma unroll
        for (int j = 0; j < 4; ++j) {
            const int col = bn + tc * 4 + j;
            XW[row * DH + col] = acc[i][j] + b[col];
        }
    }
}

// ---------------- Kernel B (R9): contribution-passing --------------------
// 256 wgs x 512 thr. bid -> xcd=bid&7, seq=xcd*8+((bid>>3)&7), part=bid>>6
// (4 parts of a seq share bid%8 -> same XCD under round-robin; heuristic
// only, correctness placement-independent).
// Thread tid == global col j. wv[128] = Wh[128*part + kk][tid] (coalesced).
// Owner threads: tid>>7 == part (waves 2p, 2p+1). hbuf layout:
// [2][64][512][3] u64: col j's 3 remote-contrib slots are adjacent (24B).
__global__ __launch_bounds__(512, 2) void rnn_rec9(
    const float* __restrict__ Wh,            // (512, 512)
    const float* __restrict__ h0,            // (64, 512)
    float* __restrict__ out,                 // (64, 512, 512); xw on entry
    unsigned long long* __restrict__ hbuf)   // [2][64][512][3] tagged contribs
{
    __shared__ float hpiece[2][128];         // double-buffered own h piece

    const int bid  = blockIdx.x;
    const int xcd  = bid & 7;
    const int idx  = bid >> 3;
    const int seq  = xcd * 8 + (idx & 7);
    const int part = idx >> 3;               // 0..3
    const int tid  = threadIdx.x;            // global col j
    const int kbase = part * 128;

    // ---- one-time: Wh[k-slice][tid] into registers (coalesced), pinned ----
    float wv[128];
    #pragma unroll
    for (int kk = 0; kk < 128; ++kk)
        wv[kk] = Wh[(size_t)(kbase + kk) * DH + tid];
    #pragma unroll
    for (int kk = 0; kk < 128; ++kk)
        asm volatile("" : "+v"(wv[kk]));

    const int  pj       = tid >> 7;                   // owner part of col tid
    const bool is_owner = (pj == part);               // wave-uniform
    const int  isl      = part - (part > pj ? 1 : 0); // publisher slot 0..2

    if (tid < 128) hpiece[0][tid] = h0[(size_t)seq * DH + kbase + tid];

    float* __restrict__ outn = out + (size_t)seq * TSTEPS * DH;
    float xw_cur    = is_owner ? outn[tid] : 0.0f;    // xw[0][tid]
    float hval_prev = 0.0f;

    // per-(seq,col) slot bases for the two buffers
    unsigned long long* const sb0 = hbuf + ((size_t)(0 * NSEQ + seq) * DH + tid) * 3;
    unsigned long long* const sb1 = hbuf + ((size_t)(1 * NSEQ + seq) * DH + tid) * 3;

    __syncthreads();

    for (int t = 0; t < TSTEPS; ++t) {
        const int buf = t & 1;
        const float* hp = hpiece[buf];

        // ---- local partial dot: own 128 k's x own col (LDS broadcast h) ----
        float a0 = 0.0f, a1 = 0.0f, a2 = 0.0f, a3 = 0.0f;
        #pragma unroll
        for (int kk = 0; kk < 128; kk += 4) {
            const float4 h4 = *(const float4*)&hp[kk];
            a0 = fmaf(h4.x, wv[kk + 0], a0);
            a1 = fmaf(h4.y, wv[kk + 1], a1);
            a2 = fmaf(h4.z, wv[kk + 2], a2);
            a3 = fmaf(h4.w, wv[kk + 3], a3);
        }
        const float contrib = (a0 + a1) + (a2 + a3);

        unsigned long long* const sb = buf ? sb1 : sb0;
        const unsigned want = (unsigned)(t + 1);

        if (!is_owner) {
            // ---- publisher: fire-and-forget tagged contrib; drain overlaps
            //      the owners' poll (publishers hit the barrier early) ----
            const unsigned long long v =
                ((unsigned long long)want << 32) |
                (unsigned long long)__float_as_uint(contrib);
            __hip_atomic_store(sb + isl, v, __ATOMIC_RELAXED,
                               __HIP_MEMORY_SCOPE_AGENT);
        } else {
            // deferred out-store of h_{t-1}: drains during the poll below,
            // keeping the pre-barrier vmcnt(0) off the critical path
            if (t > 0) outn[(size_t)(t - 1) * DH + tid] = hval_prev;
            float xw_next = (t < TSTEPS - 1) ? outn[(size_t)(t + 1) * DH + tid]
                                             : 0.0f;
            // ---- poll 3 adjacent slots (one cache line, ~1 RTT/round) ----
            unsigned long long v0, v1, v2;
            do {
                v0 = __hip_atomic_load(sb + 0, __ATOMIC_RELAXED,
                                       __HIP_MEMORY_SCOPE_AGENT);
                v1 = __hip_atomic_load(sb + 1, __ATOMIC_RELAXED,
                                       __HIP_MEMORY_SCOPE_AGENT);
                v2 = __hip_atomic_load(sb + 2, __ATOMIC_RELAXED,
                                       __HIP_MEMORY_SCOPE_AGENT);
            } while ((unsigned)(v0 >> 32) < want ||
                     (unsigned)(v1 >> 32) < want ||
                     (unsigned)(v2 >> 32) < want);
            // ---- finish: 3 adds + xw + tanh (fixed per-thread order) ----
            const float z = xw_cur
                + ((contrib + __uint_as_float((unsigned)v0))
                 + (__uint_as_float((unsigned)v1) + __uint_as_float((unsigned)v2)));
            hval_prev = tanhf(z);
            hpiece[buf ^ 1][tid & 127] = hval_prev;  // next step's h piece
            xw_cur = xw_next;
        }
        __syncthreads();   // the only barrier per step
    }
    if (is_owner) outn[(size_t)(TSTEPS - 1) * DH + tid] = hval_prev;
}

// ---------------- Mid fallback (R5 kernel, h-passing, L3-only) --------------
__global__ __launch_bounds__(512, 2) void rnn_rec5(
    const float* __restrict__ Wh,
    const float* __restrict__ h0,
    float* __restrict__ out,
    unsigned long long* __restrict__ hbuf)
{
    __shared__ float hslice[8][64];
    __shared__ float partb[2][8][128];

    const int bid  = blockIdx.x;
    const int xcd  = bid & 7;
    const int idx  = bid >> 3;
    const int seq  = xcd * 8 + (idx & 7);
    const int part = idx >> 3;
    const int tid  = threadIdx.x;
    const int lane = tid & 63;
    const int s    = tid >> 6;
    const int colbase = part * 128;
    const int c0   = colbase + lane * 2;

    v2f wv[64];
    #pragma unroll
    for (int k = 0; k < 64; ++k)
        wv[k] = *(const v2f*)&Wh[(size_t)(s * 64 + k) * DH + c0];
    #pragma unroll
    for (int k = 0; k < 64; ++k)
        asm volatile("" : "+v"(wv[k]));

    const int rwave = s - 2 * part;
    const bool is_reducer = (rwave == 0) | (rwave == 1);
    const int q     = rwave * 64 + lane;
    const int mycol = colbase + q;
    const int slot  = s * 64 + lane;

    hslice[s][lane] = h0[(size_t)seq * DH + slot];

    float* __restrict__ outn = out + (size_t)seq * TSTEPS * DH;
    float xw_cur = is_reducer ? outn[mycol] : 0.0f;

    for (int t = 0; t < TSTEPS; ++t) {
        const int buf = t & 1;
        v2f acc = {0.0f, 0.0f};
        #pragma unroll
        for (int qq = 0; qq < 16; ++qq) {
            const float4 h4 = *(const float4*)&hslice[s][qq * 4];
            v2f hb;
            hb.x = h4.x; hb.y = h4.x; acc = __builtin_elementwise_fma(hb, wv[4*qq+0], acc);
            hb.x = h4.y; hb.y = h4.y; acc = __builtin_elementwise_fma(hb, wv[4*qq+1], acc);
            hb.x = h4.z; hb.y = h4.z; acc = __builtin_elementwise_fma(hb, wv[4*qq+2], acc);
            hb.x = h4.w; hb.y = h4.w; acc = __builtin_elementwise_fma(hb, wv[4*qq+3], acc);
        }
        *(v2f*)&partb[buf][s][lane * 2] = acc;
        __syncthreads();

        unsigned long long* hb64 = &hbuf[((size_t)buf * NSEQ + seq) * DH];
        if (is_reducer) {
            float ssum = partb[buf][0][q] + partb[buf][1][q]
                       + partb[buf][2][q] + partb[buf][3][q]
                       + partb[buf][4][q] + partb[buf][5][q]
                       + partb[buf][6][q] + partb[buf][7][q];
            const float hval = tanhf(xw_cur + ssum);
            if (t < TSTEPS - 1) {
                const unsigned long long v =
                    ((unsigned long long)(unsigned)(t + 1) << 32) |
                    (unsigned long long)__float_as_uint(hval);
                __hip_atomic_store(&hb64[mycol], v,
                                   __ATOMIC_RELAXED, __HIP_MEMORY_SCOPE_AGENT);
            }
            hslice[s][lane] = hval;
            outn[(size_t)t * DH + mycol] = hval;
            if (t < TSTEPS - 1)
                xw_cur = outn[(size_t)(t + 1) * DH + mycol];
        } else if (t < TSTEPS - 1) {
            unsigned long long v;
            do {
                v = __hip_atomic_load(&hb64[slot], __ATOMIC_RELAXED,
                                      __HIP_MEMORY_SCOPE_AGENT);
            } while ((unsigned)(v >> 32) < (unsigned)(t + 1));
            hslice[s][lane] = __uint_as_float((unsigned)v);
        }
    }
}

// ---------------- Last-resort fallback (R1 kernel) --------------------------
__global__ __launch_bounds__(1024) void rnn_rec(
    const float* __restrict__ Wh,
    const float* __restrict__ h0,
    float* __restrict__ out)
{
    __shared__ float hsh[DH];
    __shared__ float part[8][DH];

    const int n     = blockIdx.x;
    const int tid   = threadIdx.x;
    const int jgrp  = tid & 127;
    const int ks    = tid >> 7;
    const int kbase = ks * 64;

    if (tid < DH) hsh[tid] = h0[(size_t)n * DH + tid];
    __syncthreads();

    const float4* __restrict__ Wh4 = (const float4*)Wh;
    float* __restrict__ outn = out + (size_t)n * TSTEPS * DH;

    float xw_cur = (tid < DH) ? outn[tid] : 0.0f;

    for (int t = 0; t < TSTEPS; ++t) {
        float xw_next = 0.0f;
        if (tid < DH && t < TSTEPS - 1) xw_next = outn[(size_t)(t + 1) * DH + tid];

        float4 acc = {0.0f, 0.0f, 0.0f, 0.0f};
        #pragma unroll 8
        for (int k = 0; k < 64; ++k) {
            const float hk = hsh[kbase + k];
            const float4 w = Wh4[(size_t)(kbase + k) * 128 + jgrp];
            acc.x += hk * w.x; acc.y += hk * w.y;
            acc.z += hk * w.z; acc.w += hk * w.w;
        }
        *(float4*)&part[ks][jgrp * 4] = acc;
        __syncthreads();

        if (tid < DH) {
            const int j = tid;
            float sum = part[0][j] + part[1][j] + part[2][j] + part[3][j]
                      + part[4][j] + part[5][j] + part[6][j] + part[7][j];
            const float hv = tanhf(xw_cur + sum);
            hsh[j] = hv;
            outn[(size_t)t * DH + j] = hv;
            xw_cur = xw_next;
        }
        __syncthreads();
    }
}

extern "C" void kernel_launch(void* const* d_in, const int* in_sizes, int n_in,
                              void* d_out, int out_size, void* d_ws, size_t ws_size,
                              hipStream_t stream) {
    const float* x  = (const float*)d_in[0];  // (64, 512, 512)
    const float* h0 = (const float*)d_in[1];  // (64, 512)
    const float* Wx = (const float*)d_in[2];  // (512, 512)
    const float* Wh = (const float*)d_in[3];  // (512, 512)
    const float* b  = (const float*)d_in[4];  // (512,)
    float* out = (float*)d_out;               // (64, 512, 512)

    // Kernel A: xw = x @ Wx + b, written into d_out.
    xw_gemm<<<dim3(MTOT / 64, DH / 64), 256, 0, stream>>>(x, Wx, b, out);

    // Workspace needs: rec9 = [2][64][512][3] u64 = 1.5 MB (zeroed per launch
    // so step-0 polls see tag 0 < 1; graph-replay deterministic).
    const size_t rec9_bytes = (size_t)2 * NSEQ * DH * 3 * sizeof(unsigned long long);
    const size_t rec5_bytes = (size_t)2 * NSEQ * DH * sizeof(unsigned long long);
    if (ws_size >= rec9_bytes) {
        unsigned long long* hbuf = (unsigned long long*)d_ws;
        hipMemsetAsync(hbuf, 0, rec9_bytes, stream);
        rnn_rec9<<<256, 512, 0, stream>>>(Wh, h0, out, hbuf);
    } else if (ws_size >= rec5_bytes) {
        unsigned long long* hbuf = (unsigned long long*)d_ws;
        hipMemsetAsync(hbuf, 0, rec5_bytes, stream);
        rnn_rec5<<<256, 512, 0, stream>>>(Wh, h0, out, hbuf);
    } else {
        rnn_rec<<<NSEQ, 1024, 0, stream>>>(Wh, h0, out);
    }
}

// Round 10
// 964.316 us; speedup vs baseline: 1.7449x; 1.7449x over previous
//
#include <hip/hip_runtime.h>
#include <hip/hip_bf16.h>
#include <cmath>

// Problem: N=64, T=512, D=512, H=512
//   xw = x @ Wx + b                 (parallel GEMM, kernel A -> d_out)
//   h_t = tanh(xw_t + h_{t-1} @ Wh) (sequential, kernel B)
//
// R10 = R5 (best so far, 705us rnn) with three latency refinements, no
// protocol changes:
//  1. Raw s_barrier + explicit lgkmcnt(0) instead of __syncthreads: drops the
//     compiler's pre-barrier s_waitcnt vmcnt(0) drain, so the reducer's xw
//     prefetch (HBM ~900cy) and out-store acks ride fully off the ring.
//  2. Publish slot-reuse guard = vmcnt(0) placed immediately BEFORE the
//     publish (waits only for ops issued ~1 ring ago, i.e. ~free) instead of
//     relying on __syncthreads' drain.
//  3. 2-deep software-pipelined polls: two outstanding atomic loads; checking
//     the older one lets the compiler wait at vmcnt(1), halving the ~900cy
//     poll-RTT discovery quantization.
// Ring model (calibrated on R4-R9): 250 publish + ~2400 transit/poll + ~650
// compute = 3300cy (R5 measured 3.3e3). Items 1-3 target ~400-600cy.
// L2-exchange (R6 sc0-load, R8 wg-scope RMW) and contribution-passing (R9)
// are REFUTED on gfx950 -- do not revisit.

#define DH     512
#define NSEQ   64
#define TSTEPS 512
#define MTOT   32768   // N*T

typedef float v2f __attribute__((ext_vector_type(2)));

// ---------------- Kernel A: xw = x @ Wx + b  (fp32 LDS-tiled GEMM) ----------
__global__ __launch_bounds__(256) void xw_gemm(
    const float* __restrict__ X,    // (32768, 512)
    const float* __restrict__ Wx,   // (512, 512)
    const float* __restrict__ b,    // (512,)
    float* __restrict__ XW)         // (32768, 512) == d_out
{
    __shared__ float As[16][64];
    __shared__ float Bs[16][64];

    const int bm = blockIdx.x * 64;
    const int bn = blockIdx.y * 64;
    const int tid = threadIdx.x;
    const int tr = tid >> 4;
    const int tc = tid & 15;

    float acc[4][4] = {};

    for (int k0 = 0; k0 < DH; k0 += 16) {
        {
            int m  = tid >> 2;
            int kk = (tid & 3) * 4;
            const float4 v = *(const float4*)&X[(size_t)(bm + m) * DH + k0 + kk];
            As[kk + 0][m] = v.x; As[kk + 1][m] = v.y;
            As[kk + 2][m] = v.z; As[kk + 3][m] = v.w;
        }
        {
            int k  = tid >> 4;
            int j4 = (tid & 15) * 4;
            *(float4*)&Bs[k][j4] = *(const float4*)&Wx[(size_t)(k0 + k) * DH + bn + j4];
        }
        __syncthreads();

        #pragma unroll
        for (int k = 0; k < 16; ++k) {
            float a0 = As[k][tr * 4 + 0], a1 = As[k][tr * 4 + 1];
            float a2 = As[k][tr * 4 + 2], a3 = As[k][tr * 4 + 3];
            float b0 = Bs[k][tc * 4 + 0], b1 = Bs[k][tc * 4 + 1];
            float b2 = Bs[k][tc * 4 + 2], b3 = Bs[k][tc * 4 + 3];
            acc[0][0] += a0 * b0; acc[0][1] += a0 * b1; acc[0][2] += a0 * b2; acc[0][3] += a0 * b3;
            acc[1][0] += a1 * b0; acc[1][1] += a1 * b1; acc[1][2] += a1 * b2; acc[1][3] += a1 * b3;
            acc[2][0] += a2 * b0; acc[2][1] += a2 * b1; acc[2][2] += a2 * b2; acc[2][3] += a2 * b3;
            acc[3][0] += a3 * b0; acc[3][1] += a3 * b1; acc[3][2] += a3 * b2; acc[3][3] += a3 * b3;
        }
        __syncthreads();
    }

    #pragma unroll
    for (int i = 0; i < 4; ++i) {
        const size_t row = (size_t)(bm + tr * 4 + i);
        #pragma unroll
        for (int j = 0; j < 4; ++j) {
            const int col = bn + tc * 4 + j;
            XW[row * DH + col] = acc[i][j] + b[col];
        }
    }
}

// Raw workgroup barrier: LDS-visibility only (no vmcnt drain).
__device__ __forceinline__ void wg_barrier_lds() {
    asm volatile("s_waitcnt lgkmcnt(0)" ::: "memory");
    __builtin_amdgcn_s_barrier();
    asm volatile("" ::: "memory");
}

// ---------------- Kernel B (R10): R5 protocol, drain-free -------------------
// 256 wgs x 512 thr. bid -> xcd=bid&7, seq=xcd*8+((bid>>3)&7), part=bid>>6.
// Waves: lane=tid&63, s=tid>>6; wave s holds Wh k-slice [s*64,+64) x the wg's
// 128 cols register-resident (v2f wv[64], pinned). Reducer waves
// (s==2*part+r): own reduce output == own FMA h-slice (slot==mycol).
// Remote waves: 2-deep pipelined poll of tagged slot s*64+lane.
__global__ __launch_bounds__(512, 2) void rnn_rec10(
    const float* __restrict__ Wh,            // (512, 512)
    const float* __restrict__ h0,            // (64, 512)
    float* __restrict__ out,                 // (64, 512, 512); xw on entry
    unsigned long long* __restrict__ hbuf)   // (2, 64, 512) tagged h (d_ws)
{
    __shared__ float hslice[8][64];          // wave-private h slices
    __shared__ float partb[2][8][128];       // double-buffered partials

    const int bid  = blockIdx.x;
    const int xcd  = bid & 7;
    const int idx  = bid >> 3;
    const int seq  = xcd * 8 + (idx & 7);
    const int part = idx >> 3;               // 0..3
    const int tid  = threadIdx.x;
    const int lane = tid & 63;
    const int s    = tid >> 6;                // wave 0..7
    const int colbase = part * 128;
    const int c0   = colbase + lane * 2;

    // ---- one-time: weight slice into registers, pinned ----
    v2f wv[64];
    #pragma unroll
    for (int k = 0; k < 64; ++k)
        wv[k] = *(const v2f*)&Wh[(size_t)(s * 64 + k) * DH + c0];
    #pragma unroll
    for (int k = 0; k < 64; ++k)
        asm volatile("" : "+v"(wv[k]));

    const int rwave = s - 2 * part;
    const bool is_reducer = (rwave == 0) | (rwave == 1);
    const int q     = rwave * 64 + lane;      // col within part (reducer only)
    const int mycol = colbase + q;            // == slot for reducer waves
    const int slot  = s * 64 + lane;          // h index this lane feeds

    hslice[s][lane] = h0[(size_t)seq * DH + slot];

    float* __restrict__ outn = out + (size_t)seq * TSTEPS * DH;
    float xw_cur = is_reducer ? outn[mycol] : 0.0f;

    for (int t = 0; t < TSTEPS; ++t) {
        const int buf = t & 1;

        // ---- phase A: partial FMA over own k-slice (all 8 waves) ----
        v2f acc = {0.0f, 0.0f};
        #pragma unroll
        for (int qq = 0; qq < 16; ++qq) {
            const float4 h4 = *(const float4*)&hslice[s][qq * 4];
            v2f hb;
            hb.x = h4.x; hb.y = h4.x; acc = __builtin_elementwise_fma(hb, wv[4*qq+0], acc);
            hb.x = h4.y; hb.y = h4.y; acc = __builtin_elementwise_fma(hb, wv[4*qq+1], acc);
            hb.x = h4.z; hb.y = h4.z; acc = __builtin_elementwise_fma(hb, wv[4*qq+2], acc);
            hb.x = h4.w; hb.y = h4.w; acc = __builtin_elementwise_fma(hb, wv[4*qq+3], acc);
        }
        *(v2f*)&partb[buf][s][lane * 2] = acc;

        // LDS-only barrier: NO vmcnt drain (xw prefetch / out-store acks and
        // the in-flight publish from t-1 stay queued, off the ring).
        wg_barrier_lds();

        unsigned long long* hb64 = &hbuf[((size_t)buf * NSEQ + seq) * DH];
        if (is_reducer) {
            // reduce ASAP (left-assoc chain identical to R5 => bit-identical)
            float ssum = partb[buf][0][q] + partb[buf][1][q]
                       + partb[buf][2][q] + partb[buf][3][q]
                       + partb[buf][4][q] + partb[buf][5][q]
                       + partb[buf][6][q] + partb[buf][7][q];
            const float hval = tanhf(xw_cur + ssum);
            if (t < TSTEPS - 1) {
                const unsigned long long v =
                    ((unsigned long long)(unsigned)(t + 1) << 32) |
                    (unsigned long long)__float_as_uint(hval);
                // slot-reuse guard: drain everything older (publish@t-2 to this
                // address, xw load@t-1, out store@t-1 -- all ~1 ring old => ~free)
                asm volatile("s_waitcnt vmcnt(0)" ::: "memory");
                __hip_atomic_store(&hb64[mycol], v,
                                   __ATOMIC_RELAXED, __HIP_MEMORY_SCOPE_AGENT);
            }
            hslice[s][lane] = hval;           // own next-step data (slot==mycol)
            outn[(size_t)t * DH + mycol] = hval;          // fire-and-forget
            if (t < TSTEPS - 1)
                xw_cur = outn[(size_t)(t + 1) * DH + mycol];  // latency hidden
        } else if (t < TSTEPS - 1) {
            // ---- 2-deep pipelined poll (checks older of 2 outstanding) ----
            const unsigned want = (unsigned)(t + 1);
            unsigned long long* sp = &hb64[slot];
            unsigned long long p0 = __hip_atomic_load(sp, __ATOMIC_RELAXED,
                                                      __HIP_MEMORY_SCOPE_AGENT);
            unsigned long long p1 = __hip_atomic_load(sp, __ATOMIC_RELAXED,
                                                      __HIP_MEMORY_SCOPE_AGENT);
            unsigned long long v;
            while (true) {
                if ((unsigned)(p0 >> 32) >= want) { v = p0; break; }
                p0 = p1;
                p1 = __hip_atomic_load(sp, __ATOMIC_RELAXED,
                                       __HIP_MEMORY_SCOPE_AGENT);
            }
            hslice[s][lane] = __uint_as_float((unsigned)v);
        }
        // no second barrier: hslice wave-private, partb double-buffered
    }
}

// ---------------- Last-resort fallback (R1 kernel) --------------------------
__global__ __launch_bounds__(1024) void rnn_rec(
    const float* __restrict__ Wh,
    const float* __restrict__ h0,
    float* __restrict__ out)
{
    __shared__ float hsh[DH];
    __shared__ float part[8][DH];

    const int n     = blockIdx.x;
    const int tid   = threadIdx.x;
    const int jgrp  = tid & 127;
    const int ks    = tid >> 7;
    const int kbase = ks * 64;

    if (tid < DH) hsh[tid] = h0[(size_t)n * DH + tid];
    __syncthreads();

    const float4* __restrict__ Wh4 = (const float4*)Wh;
    float* __restrict__ outn = out + (size_t)n * TSTEPS * DH;

    float xw_cur = (tid < DH) ? outn[tid] : 0.0f;

    for (int t = 0; t < TSTEPS; ++t) {
        float xw_next = 0.0f;
        if (tid < DH && t < TSTEPS - 1) xw_next = outn[(size_t)(t + 1) * DH + tid];

        float4 acc = {0.0f, 0.0f, 0.0f, 0.0f};
        #pragma unroll 8
        for (int k = 0; k < 64; ++k) {
            const float hk = hsh[kbase + k];
            const float4 w = Wh4[(size_t)(kbase + k) * 128 + jgrp];
            acc.x += hk * w.x; acc.y += hk * w.y;
            acc.z += hk * w.z; acc.w += hk * w.w;
        }
        *(float4*)&part[ks][jgrp * 4] = acc;
        __syncthreads();

        if (tid < DH) {
            const int j = tid;
            float sum = part[0][j] + part[1][j] + part[2][j] + part[3][j]
                      + part[4][j] + part[5][j] + part[6][j] + part[7][j];
            const float hv = tanhf(xw_cur + sum);
            hsh[j] = hv;
            outn[(size_t)t * DH + j] = hv;
            xw_cur = xw_next;
        }
        __syncthreads();
    }
}

extern "C" void kernel_launch(void* const* d_in, const int* in_sizes, int n_in,
                              void* d_out, int out_size, void* d_ws, size_t ws_size,
                              hipStream_t stream) {
    const float* x  = (const float*)d_in[0];  // (64, 512, 512)
    const float* h0 = (const float*)d_in[1];  // (64, 512)
    const float* Wx = (const float*)d_in[2];  // (512, 512)
    const float* Wh = (const float*)d_in[3];  // (512, 512)
    const float* b  = (const float*)d_in[4];  // (512,)
    float* out = (float*)d_out;               // (64, 512, 512)

    // Kernel A: xw = x @ Wx + b, written into d_out.
    xw_gemm<<<dim3(MTOT / 64, DH / 64), 256, 0, stream>>>(x, Wx, b, out);

    // Workspace: hbuf = (2, 64, 512) u64 tagged slots = 512 KB, zeroed per
    // launch (tag 0 < 1 => step-0 polls can't see stale; graph-replay safe).
    const size_t hbuf_bytes = (size_t)2 * NSEQ * DH * sizeof(unsigned long long);
    if (ws_size >= hbuf_bytes) {
        unsigned long long* hbuf = (unsigned long long*)d_ws;
        hipMemsetAsync(hbuf, 0, hbuf_bytes, stream);
        rnn_rec10<<<256, 512, 0, stream>>>(Wh, h0, out, hbuf);
    } else {
        rnn_rec<<<NSEQ, 1024, 0, stream>>>(Wh, h0, out);
    }
}

// Round 12
// 793.170 us; speedup vs baseline: 2.1214x; 1.2158x over previous
//
#include <hip/hip_runtime.h>
#include <hip/hip_bf16.h>
#include <cmath>

// Problem: N=64, T=512, D=512, H=512
//   xw = x @ Wx + b ; h_t = tanh(xw_t + h_{t-1} @ Wh)
//
// R12: SELF-FUSED ring. 256 wgs x 512 thr (the proven R5 h-ring, 705us).
// wg (seq,part) also produces its OWN xw slice (seq, all t, part's 128 cols)
// inside the ring's idle windows -- no extra wgs, no cross-wg xw dependency,
// deadlock-impossible (R11's counter-gated producer grid deadlocked: B-wgs
// spun while A-wgs were never scheduled; G16 co-residency violation).
//  - xw built tile-by-tile (64 t-rows x 128 cols, K=512 as 64 chunks of 8):
//    one chunk per ring step = 128 FMA/thread in the ~1600cy L3 transit gap
//    (reducers: after publish; non-reducers: before poll).
//  - X/Wx chunk staging (2KB+4KB) register-prefetched one step ahead, LDS
//    double-buffered by t&1; barrier-race-free (write@t pre-bar, read@t
//    post-bar, rewrite@t+2 pre-bar: barrier t+1 separates).
//  - xw tiles live in LDS [2][64][128] (tile rb in buf rb&1; write step
//    64rb-1 post-bar, first read step 64rb post-bar: barrier separates).
//    xw NEVER touches HBM; out receives only h.
//  - prologue builds tile 0 (~64 chunked iterations, ~25us).
// Ring protocol (tags, buffers, publishes, polls) is R5 VERBATIM.
// DEAD ENDS (do not revisit): L2 exchange via sc0 loads (R6) or wg-scope RMW
// (R8); 2-seq interleave (R7); contribution-passing (R9); drain-free barrier
// + pipelined polls (R10); separate producer grid with gating (R11).

#define DH     512
#define NSEQ   64
#define TSTEPS 512
#define MTOT   32768   // N*T

typedef float v2f __attribute__((ext_vector_type(2)));

// 8k-chunk GEMM micro-tile: accg[8][2] += xstage[SB] (8 rows/wave) x wstage[SB]
#define GEMM_CHUNK(SB)                                                         \
    {                                                                          \
        float2 w2[8];                                                          \
        _Pragma("unroll")                                                      \
        for (int kk = 0; kk < 8; ++kk)                                         \
            w2[kk] = *(const float2*)&wstage[SB][kk][gc * 2];                  \
        _Pragma("unroll")                                                      \
        for (int r = 0; r < 8; ++r) {                                          \
            const float4 xa = *(const float4*)&xstage[SB][rg * 8 + r][0];      \
            const float4 xb = *(const float4*)&xstage[SB][rg * 8 + r][4];      \
            accg[r][0] = fmaf(xa.x, w2[0].x, accg[r][0]);                      \
            accg[r][1] = fmaf(xa.x, w2[0].y, accg[r][1]);                      \
            accg[r][0] = fmaf(xa.y, w2[1].x, accg[r][0]);                      \
            accg[r][1] = fmaf(xa.y, w2[1].y, accg[r][1]);                      \
            accg[r][0] = fmaf(xa.z, w2[2].x, accg[r][0]);                      \
            accg[r][1] = fmaf(xa.z, w2[2].y, accg[r][1]);                      \
            accg[r][0] = fmaf(xa.w, w2[3].x, accg[r][0]);                      \
            accg[r][1] = fmaf(xa.w, w2[3].y, accg[r][1]);                      \
            accg[r][0] = fmaf(xb.x, w2[4].x, accg[r][0]);                      \
            accg[r][1] = fmaf(xb.x, w2[4].y, accg[r][1]);                      \
            accg[r][0] = fmaf(xb.y, w2[5].x, accg[r][0]);                      \
            accg[r][1] = fmaf(xb.y, w2[5].y, accg[r][1]);                      \
            accg[r][0] = fmaf(xb.z, w2[6].x, accg[r][0]);                      \
            accg[r][1] = fmaf(xb.z, w2[6].y, accg[r][1]);                      \
            accg[r][0] = fmaf(xb.w, w2[7].x, accg[r][0]);                      \
            accg[r][1] = fmaf(xb.w, w2[7].y, accg[r][1]);                      \
        }                                                                      \
    }

__global__ __launch_bounds__(512, 2) void rnn_fused2(
    const float* __restrict__ X,     // (32768, 512)
    const float* __restrict__ Wx,    // (512, 512)
    const float* __restrict__ bias,  // (512,)
    const float* __restrict__ Wh,    // (512, 512)
    const float* __restrict__ h0,    // (64, 512)
    float* __restrict__ out,         // (64, 512, 512) -- receives h only
    unsigned long long* __restrict__ hbuf)  // (2, 64, 512) tagged h (d_ws)
{
    __shared__ float xwtile[2][64][128];   // 64 KB: xw tile ring (tile rb -> buf rb&1)
    __shared__ float hslice[8][64];        //  2 KB: wave-private h slices
    __shared__ float partb[2][8][128];     //  4 KB: ring partials (dbuf by t&1)
    __shared__ float xstage[2][64][8];     //  4 KB: X chunk stage (dbuf by t&1)
    __shared__ float wstage[2][8][128];    //  8 KB: Wx chunk stage

    const int bid  = blockIdx.x;
    const int xcd  = bid & 7;
    const int idx  = bid >> 3;
    const int seq  = xcd * 8 + (idx & 7);
    const int part = idx >> 3;               // 0..3
    const int tid  = threadIdx.x;
    const int lane = tid & 63;
    const int s    = tid >> 6;                // wave 0..7
    const int colbase = part * 128;
    const int c0   = colbase + lane * 2;

    // ---- ring weights: Wh k-slice [s*64,+64) x 128 cols, register-pinned ----
    v2f wv[64];
    #pragma unroll
    for (int k = 0; k < 64; ++k)
        wv[k] = *(const v2f*)&Wh[(size_t)(s * 64 + k) * DH + c0];
    #pragma unroll
    for (int k = 0; k < 64; ++k)
        asm volatile("" : "+v"(wv[k]));

    const int rwave = s - 2 * part;
    const bool is_reducer = (rwave == 0) | (rwave == 1);
    const int q     = rwave * 64 + lane;      // col within part (reducer only)
    const int mycol = colbase + q;            // == slot for reducer waves
    const int slot  = s * 64 + lane;          // h index this lane feeds

    hslice[s][lane] = h0[(size_t)seq * DH + slot];
    const float bias_r = is_reducer ? bias[mycol] : 0.0f;

    float* __restrict__ outn = out + (size_t)seq * TSTEPS * DH;
    const float* __restrict__ Xn = X + (size_t)seq * TSTEPS * DH;

    // ---- GEMM thread mapping ----
    const int gc  = lane;        // local col pair (2gc, 2gc+1)
    const int rg  = s;           // local rows rg*8 .. rg*8+7
    const int sxr = tid >> 3, sxk = tid & 7;   // X stage: [row][k]
    const int swk = tid >> 6, swc = tid & 63;  // Wx stage: [k][colpair]

    float accg[8][2];
    #pragma unroll
    for (int r = 0; r < 8; ++r) { accg[r][0] = 0.0f; accg[r][1] = 0.0f; }

    // ---------------- prologue: build xw tile 0 ------------------------------
    // iter u: stage chunk u (pre-barrier) -> barrier -> compute chunk u.
    // stage[u&1] rewritten at u+2 pre-barrier; read at u post-barrier:
    // barrier(u+1) separates -> race-free.
    for (int u = 0; u < 64; ++u) {
        const float  pxv = Xn[(size_t)sxr * DH + u * 8 + sxk];
        const float2 pwv = *(const float2*)&Wx[(size_t)(u * 8 + swk) * DH + colbase + swc * 2];
        xstage[u & 1][sxr][sxk] = pxv;
        *(float2*)&wstage[u & 1][swk][swc * 2] = pwv;
        __syncthreads();
        GEMM_CHUNK(u & 1);
    }
    #pragma unroll
    for (int r = 0; r < 8; ++r) {
        float2 v; v.x = accg[r][0]; v.y = accg[r][1];
        *(float2*)&xwtile[0][rg * 8 + r][gc * 2] = v;
        accg[r][0] = 0.0f; accg[r][1] = 0.0f;
    }
    __syncthreads();

    // prefetch stage chunk for ring step 0 (tile 1, chunk 0)
    float  pxv = Xn[(size_t)(64 + sxr) * DH + sxk];
    float2 pwv = *(const float2*)&Wx[(size_t)swk * DH + colbase + swc * 2];

    // ---------------- ring (R5 protocol + in-ring GEMM) ----------------------
    for (int t = 0; t < TSTEPS; ++t) {
        const int buf = t & 1;
        const int tb  = (t >> 6) + 1;        // tile being built this period
        const int u   = t & 63;              // chunk index
        const bool building = (tb < 8);

        // ---- ring FMA over own k-slice (all 8 waves) ----
        v2f acc = {0.0f, 0.0f};
        #pragma unroll
        for (int qq = 0; qq < 16; ++qq) {
            const float4 h4 = *(const float4*)&hslice[s][qq * 4];
            v2f hb;
            hb.x = h4.x; hb.y = h4.x; acc = __builtin_elementwise_fma(hb, wv[4*qq+0], acc);
            hb.x = h4.y; hb.y = h4.y; acc = __builtin_elementwise_fma(hb, wv[4*qq+1], acc);
            hb.x = h4.z; hb.y = h4.z; acc = __builtin_elementwise_fma(hb, wv[4*qq+2], acc);
            hb.x = h4.w; hb.y = h4.w; acc = __builtin_elementwise_fma(hb, wv[4*qq+3], acc);
        }
        *(v2f*)&partb[buf][s][lane * 2] = acc;

        // ---- stage writes from prefetched regs (vmcnt ~free: loaded @t-1) ----
        if (building) {
            xstage[buf][sxr][sxk] = pxv;
            *(float2*)&wstage[buf][swk][swc * 2] = pwv;
        }
        __syncthreads();   // the only barrier per step

        unsigned long long* hb64 = &hbuf[((size_t)buf * NSEQ + seq) * DH];
        if (is_reducer) {
            // xw from LDS tile (replaces HBM xw load); same assoc as R5:
            // (acc_gemm + b) + ssum
            const float xwv = xwtile[(t >> 6) & 1][u][q] + bias_r;
            float ssum = partb[buf][0][q] + partb[buf][1][q]
                       + partb[buf][2][q] + partb[buf][3][q]
                       + partb[buf][4][q] + partb[buf][5][q]
                       + partb[buf][6][q] + partb[buf][7][q];
            const float hval = tanhf(xwv + ssum);
            if (t < TSTEPS - 1) {
                const unsigned long long v =
                    ((unsigned long long)(unsigned)(t + 1) << 32) |
                    (unsigned long long)__float_as_uint(hval);
                __hip_atomic_store(&hb64[mycol], v,
                                   __ATOMIC_RELAXED, __HIP_MEMORY_SCOPE_AGENT);
            }
            hslice[s][lane] = hval;           // own next-step data (slot==mycol)
            outn[(size_t)t * DH + mycol] = hval;   // fire-and-forget h store
        }

        // ---- prefetch next step's stage chunk (hidden in transit window) ----
        if (building && t < 447) {           // chunk for step t+1 exists
            const int tb2 = ((t + 1) >> 6) + 1;
            const int u2  = (t + 1) & 63;
            pxv = Xn[(size_t)(tb2 * 64 + sxr) * DH + u2 * 8 + sxk];
            pwv = *(const float2*)&Wx[(size_t)(u2 * 8 + swk) * DH + colbase + swc * 2];
        }

        // ---- in-ring GEMM: chunk u of tile tb (all waves; idle-window) ----
        if (building) {
            GEMM_CHUNK(buf);
            if (u == 63) {                   // tile complete -> LDS xw ring
                #pragma unroll
                for (int r = 0; r < 8; ++r) {
                    float2 v; v.x = accg[r][0]; v.y = accg[r][1];
                    *(float2*)&xwtile[tb & 1][rg * 8 + r][gc * 2] = v;
                    accg[r][0] = 0.0f; accg[r][1] = 0.0f;
                }
            }
        }

        // ---- non-reducers: poll own tagged slot (R5 verbatim) ----
        if (!is_reducer && t < TSTEPS - 1) {
            unsigned long long v;
            do {
                v = __hip_atomic_load(&hb64[slot], __ATOMIC_RELAXED,
                                      __HIP_MEMORY_SCOPE_AGENT);
            } while ((unsigned)(v >> 32) < (unsigned)(t + 1));
            hslice[s][lane] = __uint_as_float((unsigned)v);
        }
        // no second barrier: hslice wave-private, partb/stage double-buffered
    }
}

// =================== Fallback pair (small ws) ================================
__global__ __launch_bounds__(256) void xw_gemm(
    const float* __restrict__ X, const float* __restrict__ Wx,
    const float* __restrict__ b, float* __restrict__ XW)
{
    __shared__ float As[16][64];
    __shared__ float Bs[16][64];
    const int bm = blockIdx.x * 64, bn = blockIdx.y * 64;
    const int tid = threadIdx.x, tr = tid >> 4, tc = tid & 15;
    float acc[4][4] = {};
    for (int k0 = 0; k0 < DH; k0 += 16) {
        { int m = tid >> 2, kk = (tid & 3) * 4;
          const float4 v = *(const float4*)&X[(size_t)(bm + m) * DH + k0 + kk];
          As[kk][m]=v.x; As[kk+1][m]=v.y; As[kk+2][m]=v.z; As[kk+3][m]=v.w; }
        { int k = tid >> 4, j4 = (tid & 15) * 4;
          *(float4*)&Bs[k][j4] = *(const float4*)&Wx[(size_t)(k0 + k) * DH + bn + j4]; }
        __syncthreads();
        #pragma unroll
        for (int k = 0; k < 16; ++k) {
            float a0=As[k][tr*4],a1=As[k][tr*4+1],a2=As[k][tr*4+2],a3=As[k][tr*4+3];
            float b0=Bs[k][tc*4],b1=Bs[k][tc*4+1],b2=Bs[k][tc*4+2],b3=Bs[k][tc*4+3];
            acc[0][0]+=a0*b0;acc[0][1]+=a0*b1;acc[0][2]+=a0*b2;acc[0][3]+=a0*b3;
            acc[1][0]+=a1*b0;acc[1][1]+=a1*b1;acc[1][2]+=a1*b2;acc[1][3]+=a1*b3;
            acc[2][0]+=a2*b0;acc[2][1]+=a2*b1;acc[2][2]+=a2*b2;acc[2][3]+=a2*b3;
            acc[3][0]+=a3*b0;acc[3][1]+=a3*b1;acc[3][2]+=a3*b2;acc[3][3]+=a3*b3;
        }
        __syncthreads();
    }
    #pragma unroll
    for (int i = 0; i < 4; ++i) {
        const size_t row = (size_t)(bm + tr * 4 + i);
        #pragma unroll
        for (int j = 0; j < 4; ++j)
            XW[row * DH + bn + tc * 4 + j] = acc[i][j] + b[bn + tc * 4 + j];
    }
}

__global__ __launch_bounds__(1024) void rnn_rec(
    const float* __restrict__ Wh, const float* __restrict__ h0,
    float* __restrict__ out)
{
    __shared__ float hsh[DH];
    __shared__ float part[8][DH];
    const int n = blockIdx.x, tid = threadIdx.x;
    const int jgrp = tid & 127, ks = tid >> 7, kbase = ks * 64;
    if (tid < DH) hsh[tid] = h0[(size_t)n * DH + tid];
    __syncthreads();
    const float4* __restrict__ Wh4 = (const float4*)Wh;
    float* __restrict__ outn = out + (size_t)n * TSTEPS * DH;
    float xw_cur = (tid < DH) ? outn[tid] : 0.0f;
    for (int t = 0; t < TSTEPS; ++t) {
        float xw_next = 0.0f;
        if (tid < DH && t < TSTEPS - 1) xw_next = outn[(size_t)(t + 1) * DH + tid];
        float4 acc = {0,0,0,0};
        #pragma unroll 8
        for (int k = 0; k < 64; ++k) {
            const float hk = hsh[kbase + k];
            const float4 w = Wh4[(size_t)(kbase + k) * 128 + jgrp];
            acc.x += hk*w.x; acc.y += hk*w.y; acc.z += hk*w.z; acc.w += hk*w.w;
        }
        *(float4*)&part[ks][jgrp * 4] = acc;
        __syncthreads();
        if (tid < DH) {
            float sum = part[0][tid]+part[1][tid]+part[2][tid]+part[3][tid]
                      + part[4][tid]+part[5][tid]+part[6][tid]+part[7][tid];
            const float hv = tanhf(xw_cur + sum);
            hsh[tid] = hv;
            outn[(size_t)t * DH + tid] = hv;
            xw_cur = xw_next;
        }
        __syncthreads();
    }
}

extern "C" void kernel_launch(void* const* d_in, const int* in_sizes, int n_in,
                              void* d_out, int out_size, void* d_ws, size_t ws_size,
                              hipStream_t stream) {
    const float* x  = (const float*)d_in[0];  // (64, 512, 512)
    const float* h0 = (const float*)d_in[1];  // (64, 512)
    const float* Wx = (const float*)d_in[2];  // (512, 512)
    const float* Wh = (const float*)d_in[3];  // (512, 512)
    const float* b  = (const float*)d_in[4];  // (512,)
    float* out = (float*)d_out;               // (64, 512, 512)

    // Workspace: hbuf = (2, 64, 512) u64 tagged slots = 512 KB, zeroed per
    // launch (tag 0 < 1 => step-0 polls can't see stale; graph-replay safe).
    const size_t hbuf_bytes = (size_t)2 * NSEQ * DH * sizeof(unsigned long long);
    if (ws_size >= hbuf_bytes) {
        unsigned long long* hbuf = (unsigned long long*)d_ws;
        hipMemsetAsync(hbuf, 0, hbuf_bytes, stream);
        rnn_fused2<<<256, 512, 0, stream>>>(x, Wx, b, Wh, h0, out, hbuf);
    } else {
        xw_gemm<<<dim3(MTOT / 64, DH / 64), 256, 0, stream>>>(x, Wx, b, out);
        rnn_rec<<<NSEQ, 1024, 0, stream>>>(Wh, h0, out);
    }
}